// Round 4
// baseline (964.498 us; speedup 1.0000x reference)
//
#include <hip/hip_runtime.h>
#include <cstdint>
#include <cstddef>

#pragma clang fp contract(off)

typedef unsigned int u32;
typedef unsigned long long u64;

// ---------------- threefry2x32 (JAX-exact, 20 rounds) ----------------
__host__ __device__ __forceinline__ u32 rotl32(u32 x, int r) {
  return __builtin_rotateleft32(x, (unsigned)r);   // v_alignbit_b32
}

__host__ __device__ __forceinline__ void tf2x32(u32 k0, u32 k1, u32 x0, u32 x1,
                                                u32& o0, u32& o1) {
  u32 k2 = k0 ^ k1 ^ 0x1BD11BDAu;
  x0 += k0; x1 += k1;
#define TFR(r) { x0 += x1; x1 = rotl32(x1, r); x1 ^= x0; }
  TFR(13) TFR(15) TFR(26) TFR(6)   x0 += k1; x1 += k2 + 1u;
  TFR(17) TFR(29) TFR(16) TFR(24)  x0 += k2; x1 += k0 + 2u;
  TFR(13) TFR(15) TFR(26) TFR(6)   x0 += k0; x1 += k1 + 3u;
  TFR(17) TFR(29) TFR(16) TFR(24)  x0 += k1; x1 += k2 + 4u;
  TFR(13) TFR(15) TFR(26) TFR(6)   x0 += k2; x1 += k0 + 5u;
#undef TFR
  o0 = x0; o1 = x1;
}

// partitionable random_bits: element idx -> xor of the two outputs of core(key, [0, idx])
__device__ __forceinline__ u32 bits32(u32 k0, u32 k1, u32 idx) {
  u32 a, b;
  tf2x32(k0, k1, 0u, idx, a, b);
  return a ^ b;
}

// JAX uniform [0,1): bitcast((bits>>9)|0x3F800000) - 1.0
__device__ __forceinline__ float u01f(u32 bits) {
  return __uint_as_float((bits >> 9) | 0x3F800000u) - 1.0f;
}

// ---------------- EXACT erfinv path (beta/gamma sampler only; ---------------
// ---------------- rejection-loop comparisons must not flip) ------------------
__device__ float erfinv32(float x) {
  float w = -log1pf(-(x * x));
  float p;
  if (w < 5.0f) {
    w = w - 2.5f;
    p = 2.81022636e-08f;
    p = p * w + 3.43273939e-07f;
    p = p * w + -3.5233877e-06f;
    p = p * w + -4.39150654e-06f;
    p = p * w + 0.00021858087f;
    p = p * w + -0.00125372503f;
    p = p * w + -0.00417768164f;
    p = p * w + 0.246640727f;
    p = p * w + 1.50140941f;
  } else {
    w = sqrtf(w) - 3.0f;
    p = -0.000200214257f;
    p = p * w + 0.000100950558f;
    p = p * w + 0.00134934322f;
    p = p * w + -0.00367342844f;
    p = p * w + 0.00573950773f;
    p = p * w + -0.0076224613f;
    p = p * w + 0.00943887047f;
    p = p * w + 1.00167406f;
    p = p * w + 2.83297682f;
  }
  return p * x;
}

__device__ __forceinline__ float normal_from_bits(u32 bits) {
  float f = u01f(bits);
  const float lo = __uint_as_float(0xBF7FFFFFu);  // nextafterf(-1,0)
  float u = f * 2.0f + lo;
  u = fmaxf(lo, u);
  return 1.41421356237f * erfinv32(u);
}

// ---------------- FAST noise path (k_main only) ------------------------------
// Returns p_tilde such that noise = fma(p_tilde, u, v):
//   p_tilde ~= 0.01*sqrt(2)*erfinv(u)/u
// Main branch: w = -ln2*L folded into poly variable t = L + 2.5/ln2 with
// coefficients B_i = a_i * (-ln2)^(8-i) * 0.01*sqrt(2). Tail (w>=5, |u|>0.9966)
// keeps explicit w. Error vs ref: ulp-level; feeds no comparisons.
__device__ __forceinline__ float noise_coef(u32 bits, float& u_out) {
  float f01 = u01f(bits);
  const float lo = __uint_as_float(0xBF7FFFFFu);
  float u = __builtin_fmaf(f01, 2.0f, lo);        // matches ref rounding
  u = fmaxf(lo, u);
  u_out = u;
  float x2m = __builtin_fmaf(-u, u, 1.0f);        // 1 - u^2
  float L = __log2f(x2m);                         // L = log2(1-u^2) <= 0
  float p;
  if (L > -7.2134752f) {                          // w < 5
    float t = L + 3.6067376f;                     // 2.5/ln2
    p = 2.1176800e-11f;
    p = __builtin_fmaf(p, t, -3.7320220e-10f);
    p = __builtin_fmaf(p, t, -5.5262215e-09f);
    p = __builtin_fmaf(p, t, 9.9370327e-09f);
    p = __builtin_fmaf(p, t, 7.1356898e-07f);
    p = __builtin_fmaf(p, t, 5.9044800e-06f);
    p = __builtin_fmaf(p, t, -2.8386004e-05f);
    p = __builtin_fmaf(p, t, -2.4177128e-03f);
    p = __builtin_fmaf(p, t, 2.1233136e-02f);
  } else {
    float w = L * -0.69314718f;
    float z = sqrtf(w) - 3.0f;
    p = -2.8314686e-06f;
    p = __builtin_fmaf(p, z, 1.4276572e-06f);
    p = __builtin_fmaf(p, z, 1.9082658e-05f);
    p = __builtin_fmaf(p, z, -5.1950125e-05f);
    p = __builtin_fmaf(p, z, 8.1168923e-05f);
    p = __builtin_fmaf(p, z, -1.0779792e-04f);
    p = __builtin_fmaf(p, z, 1.3348577e-04f);
    p = __builtin_fmaf(p, z, 1.4165810e-02f);
    p = __builtin_fmaf(p, z, 4.0064342e-02f);
  }
  return p;
}

// jax _gamma_one(key, alpha=0.4f, log_space=True), partitionable splits
__device__ float loggamma_alpha04(u32 k0, u32 k1) {
  const float third = (float)(1.0 / 3.0);
  float alpha = 0.4f + 1.0f;       // boost: alpha < 1 -> alpha + 1
  float d = alpha - third;
  float c = third / sqrtf(d);

  u32 key0, key1, sk0, sk1;
  tf2x32(k0, k1, 0u, 0u, key0, key1);
  tf2x32(k0, k1, 0u, 1u, sk0, sk1);
  float u_boost = u01f(bits32(sk0, sk1, 0u));
  float boost = log1pf(-u_boost) * 2.5f;

  float X, V, U;
  do {
    u32 a0, a1, b0, b1, c0, c1;
    tf2x32(key0, key1, 0u, 0u, a0, a1);
    tf2x32(key0, key1, 0u, 1u, b0, b1);
    tf2x32(key0, key1, 0u, 2u, c0, c1);
    key0 = a0; key1 = a1;
    u32 xk0 = b0, xk1 = b1;
    float x, v;
    do {
      u32 n0, n1, s0, s1;
      tf2x32(xk0, xk1, 0u, 0u, n0, n1);
      tf2x32(xk0, xk1, 0u, 1u, s0, s1);
      x = normal_from_bits(bits32(s0, s1, 0u));
      v = 1.0f + x * c;
      xk0 = n0; xk1 = n1;
    } while (v <= 0.0f);
    X = x * x;
    V = (v * v) * v;
    U = u01f(bits32(c0, c1, 0u));
  } while ((U >= 1.0f - (0.0331f * X) * X) &&
           (logf(U) >= X * 0.5f + d * ((1.0f - V) + logf(V))));

  float lg = logf(d) + logf(V);
  return lg + boost;
}

__device__ float beta_04(u32 la0, u32 la1, u32 lb0, u32 lb1, u32 i) {
  u32 ka0, ka1, kb0, kb1;
  tf2x32(la0, la1, 0u, i, ka0, ka1);
  tf2x32(lb0, lb1, 0u, i, kb0, kb1);
  float lga = loggamma_alpha04(ka0, ka1);
  float lgb = loggamma_alpha04(kb0, kb1);
  float m = fmaxf(lga, lgb);
  float ga = expf(lga - m);
  float gb = expf(lgb - m);
  return ga / (ga + gb);
}

struct RK {
  u32 sel0, sel1, pick0, pick1, la0, la1, lb0, lb1, coin0, coin1;
  u32 drop0, drop1, scl0, scl1, gm0, gm1, gs0, gs1, noi0, noi1;
};
struct AK { RK r[3]; };

// ---------------- K1: merged small kernel -----------------------------------
// blocks [0, mb): one WAVE per (round,sample), ballot-parallel B-scan (meta)
// blocks [mb, mb+gb): per-(round,gene) scale (gene)
__global__ __launch_bounds__(256) void k_small(
    const int* __restrict__ ctx, const int* __restrict__ y,
    const float* __restrict__ cont, const int* __restrict__ cat,
    AK keys, int B, int D, int ncont, int ncat, int mb,
    float* __restrict__ lam_ws, int* __restrict__ jsel_ws,
    int* __restrict__ domix_ws, float* __restrict__ scale_ws,
    float* __restrict__ gscale_ws, float* __restrict__ out,
    unsigned long long o_ctx, unsigned long long o_y,
    unsigned long long o_cont, unsigned long long o_cat) {
  if ((int)blockIdx.x >= mb) {
    // ---- gene branch ----
    int t = ((int)blockIdx.x - mb) * 256 + threadIdx.x;
    if (t >= 3 * D) return;
    int a = t / D, d = t - a * D;
    RK rk = keys.r[a];
    float ug = u01f(bits32(rk.gm0, rk.gm1, (u32)d));
    float us = u01f(bits32(rk.gs0, rk.gs1, (u32)d));
    float gs = us * 0.4f + 0.8f;
    gscale_ws[t] = (ug < 0.2f) ? gs : 1.0f;         // GENE_P
    return;
  }
  // ---- meta branch ----
  int wv = threadIdx.x >> 6;
  int lane = threadIdx.x & 63;
  int t = blockIdx.x * 4 + wv;
  if (t >= 3 * B) return;
  int a = t / B, i = t - a * B;
  RK rk = keys.r[a];
  int yi = y[i], ci = ctx[i];

  int nch = (B + 63) >> 6;
  // pass 1: candidate count (same label, different ctx)
  int cnt = 0;
  for (int c = 0; c < nch; ++c) {
    int j = (c << 6) + lane;
    bool pred = false;
    if (j < B) pred = (y[j] == yi) && (ctx[j] != ci);
    u64 m = __ballot(pred);
    cnt += __popcll(m);
  }

  float usel = u01f(bits32(rk.sel0, rk.sel1, (u32)i));
  bool mixmask = usel < 0.3f;                       // MIXUP_P
  float upick = u01f(bits32(rk.pick0, rk.pick1, (u32)i));
  int kth = min((int)floorf(upick * (float)cnt), max(cnt - 1, 0));

  // pass 2: select the (kth+1)-th candidate in ascending j
  int jsel = 0, csum = 0;
  for (int c = 0; c < nch; ++c) {
    int j = (c << 6) + lane;
    bool pred = false;
    if (j < B) pred = (y[j] == yi) && (ctx[j] != ci);
    u64 m = __ballot(pred);
    int pc = __popcll(m);
    if (csum + pc > kth) {           // wave-uniform
      int r = kth - csum;
      for (int z = 0; z < r; ++z) m &= m - 1;   // drop r lowest set bits
      jsel = (c << 6) + __builtin_ctzll(m);
      break;
    }
    csum += pc;
  }

  float lam = beta_04(rk.la0, rk.la1, rk.lb0, rk.lb1, (u32)i);
  bool domix = mixmask && (cnt > 0);
  bool coin = u01f(bits32(rk.coin0, rk.coin1, (u32)i)) < 0.5f;
  int ctxnew = (domix && !coin) ? ctx[jsel] : ci;
  float uscale = u01f(bits32(rk.scl0, rk.scl1, (u32)i));
  float scale = uscale * 0.4f + 0.8f;               // [DS_MIN, DS_MAX]

  if (lane == 0) {
    lam_ws[t] = lam;
    jsel_ws[t] = jsel;
    domix_ws[t] = domix ? 1 : 0;
    scale_ws[t] = scale;
    out[o_ctx + (size_t)t] = (float)ctxnew;
    out[o_y + (size_t)t] = (float)yi;
    for (int c2 = 0; c2 < ncont; ++c2)
      out[o_cont + (size_t)t * ncont + c2] = cont[(size_t)i * ncont + c2];
    for (int c2 = 0; c2 < ncat; ++c2)
      out[o_cat + (size_t)t * ncat + c2] = (float)cat[(size_t)i * ncat + c2];
  }
}

// ---------------- K3: main (B,D) augmentation, 16 genes/thread ---------------
__global__ __launch_bounds__(256) void k_main(
    const float* __restrict__ x, AK keys, int B, int D,
    const float* __restrict__ lam_ws, const int* __restrict__ jsel_ws,
    const int* __restrict__ domix_ws, const float* __restrict__ scale_ws,
    const float* __restrict__ gscale_ws, float* __restrict__ out) {
  int q = blockIdx.x * blockDim.x + threadIdx.x;
  int d0 = q * 16;
  if (d0 >= D) return;
  int i = blockIdx.y;
  int a = blockIdx.z;
  int t = a * B + i;
  RK rk = keys.r[a];
  float lam = lam_ws[t];          // block-uniform -> scalar loads
  int jsel = jsel_ws[t];
  int domix = domix_ws[t];
  float scale = scale_ws[t];

  const float4* xip = (const float4*)(x + (size_t)i * D + d0);
  float4 xi4[4] = {xip[0], xip[1], xip[2], xip[3]};
  float4 xj4[4] = {xi4[0], xi4[1], xi4[2], xi4[3]};
  if (domix) {
    const float4* xjp = (const float4*)(x + (size_t)jsel * D + d0);
    xj4[0] = xjp[0]; xj4[1] = xjp[1]; xj4[2] = xjp[2]; xj4[3] = xjp[3];
  }
  const float4* gp = (const float4*)(gscale_ws + (size_t)a * D + d0);
  float4 g4[4] = {gp[0], gp[1], gp[2], gp[3]};

  float oml = 1.0f - lam;
  u32 base = (u32)(i * D + d0);

  float r[16];
#pragma unroll
  for (int v4 = 0; v4 < 4; ++v4) {
    const float* xiv = (const float*)&xi4[v4];
    const float* xjv = (const float*)&xj4[v4];
    const float* gvv = (const float*)&g4[v4];
#pragma unroll
    for (int e = 0; e < 4; ++e) {
      int ee = v4 * 4 + e;
      u32 idx = base + (u32)ee;
      u32 bd = bits32(rk.drop0, rk.drop1, idx);
      bool keep = bd >= 0x33333400u;     // == u01f(bd) > 0.2f, bit-exact
      u32 bn = bits32(rk.noi0, rk.noi1, idx);
      float u;
      float pc = noise_coef(bn, u);      // noise = fma(pc, u, v)
      float bse = domix ? __builtin_fmaf(lam, xiv[e], oml * xjv[e]) : xiv[e];
      float v = keep ? bse * (scale * gvv[e]) : 0.0f;
      r[ee] = fmaxf(__builtin_fmaf(pc, u, v), 0.0f);
    }
  }
  float4* op = (float4*)(out + (size_t)a * B * D + (size_t)i * D + d0);
#pragma unroll
  for (int v4 = 0; v4 < 4; ++v4) {
    float4 o;
    o.x = r[v4 * 4 + 0]; o.y = r[v4 * 4 + 1];
    o.z = r[v4 * 4 + 2]; o.w = r[v4 * 4 + 3];
    op[v4] = o;
  }
}

// ---------------- host ----------------
extern "C" void kernel_launch(void* const* d_in, const int* in_sizes, int n_in,
                              void* d_out, int out_size, void* d_ws, size_t ws_size,
                              hipStream_t stream) {
  const float* x = (const float*)d_in[0];
  const int* ctx = (const int*)d_in[1];
  const int* y = (const int*)d_in[2];
  const float* cont = (const float*)d_in[3];
  const int* cat = (const int*)d_in[4];
  int B = in_sizes[1];
  int D = in_sizes[0] / B;
  int ncont = in_sizes[3] / B;
  int ncat = in_sizes[4] / B;

  // Host-side threefry key schedule (pure integer math; no HIP calls).
  AK keys;
  u32 b0 = 0u, b1 = 42u;  // jax.random.key(42) -> [0, 42]
  for (int a = 0; a < 3; ++a) {
    u32 k0, k1;
    tf2x32(b0, b1, 0u, (u32)a, k0, k1);             // fold_in(base, a)
    u32 m0, m1;
    tf2x32(k0, k1, 0u, 0u, m0, m1);                 // k_mix
    tf2x32(k0, k1, 0u, 1u, keys.r[a].drop0, keys.r[a].drop1);   // k_drop
    tf2x32(k0, k1, 0u, 2u, keys.r[a].scl0, keys.r[a].scl1);     // k_scale
    tf2x32(k0, k1, 0u, 3u, keys.r[a].gm0, keys.r[a].gm1);       // k_gmask
    tf2x32(k0, k1, 0u, 4u, keys.r[a].gs0, keys.r[a].gs1);       // k_gscale
    tf2x32(k0, k1, 0u, 5u, keys.r[a].noi0, keys.r[a].noi1);     // k_noise
    tf2x32(m0, m1, 0u, 0u, keys.r[a].sel0, keys.r[a].sel1);     // k_sel
    tf2x32(m0, m1, 0u, 1u, keys.r[a].pick0, keys.r[a].pick1);   // k_pick
    u32 l0, l1;
    tf2x32(m0, m1, 0u, 2u, l0, l1);                             // k_lam
    tf2x32(m0, m1, 0u, 3u, keys.r[a].coin0, keys.r[a].coin1);   // k_coin
    tf2x32(l0, l1, 0u, 0u, keys.r[a].la0, keys.r[a].la1);       // beta key_a
    tf2x32(l0, l1, 0u, 1u, keys.r[a].lb0, keys.r[a].lb1);       // beta key_b
  }

  // workspace carve-up
  float* lam_ws = (float*)d_ws;
  int* jsel_ws = (int*)(lam_ws + (size_t)3 * B);
  int* domix_ws = jsel_ws + (size_t)3 * B;
  float* scale_ws = (float*)(domix_ws + (size_t)3 * B);
  float* gscale_ws = scale_ws + (size_t)3 * B;

  float* out = (float*)d_out;
  size_t BD = (size_t)B * D;
  unsigned long long o_ctx = 3ull * BD;
  unsigned long long o_y = o_ctx + 3ull * B;
  unsigned long long o_cont = o_y + 3ull * B;
  unsigned long long o_cat = o_cont + 3ull * (size_t)B * ncont;

  // K1: merged meta (one wave per (round,sample)) + gene
  int mb = (3 * B + 3) / 4;                 // meta blocks (4 waves/block)
  int gb = (3 * D + 255) / 256;             // gene blocks
  k_small<<<mb + gb, 256, 0, stream>>>(
      ctx, y, cont, cat, keys, B, D, ncont, ncat, mb,
      lam_ws, jsel_ws, domix_ws, scale_ws, gscale_ws, out,
      o_ctx, o_y, o_cont, o_cat);

  // K3: 16 genes/thread
  int nq = (D + 15) / 16;
  dim3 grid((nq + 255) / 256, B, 3);
  k_main<<<grid, 256, 0, stream>>>(x, keys, B, D, lam_ws, jsel_ws, domix_ws,
                                   scale_ws, gscale_ws, out);
}

// Round 5
// 952.200 us; speedup vs baseline: 1.0129x; 1.0129x over previous
//
#include <hip/hip_runtime.h>
#include <cstdint>
#include <cstddef>

#pragma clang fp contract(off)

typedef unsigned int u32;
typedef unsigned long long u64;

// ---------------- threefry2x32 (JAX-exact, 20 rounds) ----------------
__host__ __device__ __forceinline__ u32 rotl32(u32 x, int r) {
  return __builtin_rotateleft32(x, (unsigned)r);   // v_alignbit_b32
}

__host__ __device__ __forceinline__ void tf2x32(u32 k0, u32 k1, u32 x0, u32 x1,
                                                u32& o0, u32& o1) {
  u32 k2 = k0 ^ k1 ^ 0x1BD11BDAu;
  x0 += k0; x1 += k1;
#define TFR(r) { x0 += x1; x1 = rotl32(x1, r); x1 ^= x0; }
  TFR(13) TFR(15) TFR(26) TFR(6)   x0 += k1; x1 += k2 + 1u;
  TFR(17) TFR(29) TFR(16) TFR(24)  x0 += k2; x1 += k0 + 2u;
  TFR(13) TFR(15) TFR(26) TFR(6)   x0 += k0; x1 += k1 + 3u;
  TFR(17) TFR(29) TFR(16) TFR(24)  x0 += k1; x1 += k2 + 4u;
  TFR(13) TFR(15) TFR(26) TFR(6)   x0 += k2; x1 += k0 + 5u;
#undef TFR
  o0 = x0; o1 = x1;
}

// partitionable random_bits: element idx -> xor of the two outputs of core(key, [0, idx])
__device__ __forceinline__ u32 bits32(u32 k0, u32 k1, u32 idx) {
  u32 a, b;
  tf2x32(k0, k1, 0u, idx, a, b);
  return a ^ b;
}

// JAX uniform [0,1): bitcast((bits>>9)|0x3F800000) - 1.0
__device__ __forceinline__ float u01f(u32 bits) {
  return __uint_as_float((bits >> 9) | 0x3F800000u) - 1.0f;
}

// ---------------- EXACT erfinv path (beta/gamma sampler only; ---------------
// ---------------- rejection-loop comparisons must not flip) ------------------
__device__ float erfinv32(float x) {
  float w = -log1pf(-(x * x));
  float p;
  if (w < 5.0f) {
    w = w - 2.5f;
    p = 2.81022636e-08f;
    p = p * w + 3.43273939e-07f;
    p = p * w + -3.5233877e-06f;
    p = p * w + -4.39150654e-06f;
    p = p * w + 0.00021858087f;
    p = p * w + -0.00125372503f;
    p = p * w + -0.00417768164f;
    p = p * w + 0.246640727f;
    p = p * w + 1.50140941f;
  } else {
    w = sqrtf(w) - 3.0f;
    p = -0.000200214257f;
    p = p * w + 0.000100950558f;
    p = p * w + 0.00134934322f;
    p = p * w + -0.00367342844f;
    p = p * w + 0.00573950773f;
    p = p * w + -0.0076224613f;
    p = p * w + 0.00943887047f;
    p = p * w + 1.00167406f;
    p = p * w + 2.83297682f;
  }
  return p * x;
}

__device__ __forceinline__ float normal_from_bits(u32 bits) {
  float f = u01f(bits);
  const float lo = __uint_as_float(0xBF7FFFFFu);  // nextafterf(-1,0)
  float u = f * 2.0f + lo;
  u = fmaxf(lo, u);
  return 1.41421356237f * erfinv32(u);
}

// ---------------- FAST noise path (k_main only) ------------------------------
// Returns p_tilde such that noise = fma(p_tilde, u, v):
//   p_tilde ~= 0.01*sqrt(2)*erfinv(u)/u
// Main branch: -ln2 and 2.5 folded into poly variable t = L + 2.5/ln2 with
// coefficients a_i * (-ln2)^(8-i) * 0.01*sqrt(2). Tail (w>=5, |u|>0.9966)
// keeps explicit w. Error vs ref: ulp-level; feeds no comparisons.
__device__ __forceinline__ float noise_coef(u32 bits, float& u_out) {
  float f01 = u01f(bits);
  const float lo = __uint_as_float(0xBF7FFFFFu);
  float u = __builtin_fmaf(f01, 2.0f, lo);        // matches ref rounding
  u = fmaxf(lo, u);
  u_out = u;
  float x2m = __builtin_fmaf(-u, u, 1.0f);        // 1 - u^2
  float L = __log2f(x2m);                         // L = log2(1-u^2) <= 0
  float p;
  if (L > -7.2134752f) {                          // w < 5
    float t = L + 3.6067376f;                     // 2.5/ln2
    p = 2.1176800e-11f;
    p = __builtin_fmaf(p, t, -3.7320220e-10f);
    p = __builtin_fmaf(p, t, -5.5262215e-09f);
    p = __builtin_fmaf(p, t, 9.9370327e-09f);
    p = __builtin_fmaf(p, t, 7.1356898e-07f);
    p = __builtin_fmaf(p, t, 5.9044800e-06f);
    p = __builtin_fmaf(p, t, -2.8386004e-05f);
    p = __builtin_fmaf(p, t, -2.4177128e-03f);
    p = __builtin_fmaf(p, t, 2.1233136e-02f);
  } else {
    float w = L * -0.69314718f;
    float z = sqrtf(w) - 3.0f;
    p = -2.8314686e-06f;
    p = __builtin_fmaf(p, z, 1.4276572e-06f);
    p = __builtin_fmaf(p, z, 1.9082658e-05f);
    p = __builtin_fmaf(p, z, -5.1950125e-05f);
    p = __builtin_fmaf(p, z, 8.1168923e-05f);
    p = __builtin_fmaf(p, z, -1.0779792e-04f);
    p = __builtin_fmaf(p, z, 1.3348577e-04f);
    p = __builtin_fmaf(p, z, 1.4165810e-02f);
    p = __builtin_fmaf(p, z, 4.0064342e-02f);
  }
  return p;
}

// jax _gamma_one(key, alpha=0.4f, log_space=True), partitionable splits
__device__ float loggamma_alpha04(u32 k0, u32 k1) {
  const float third = (float)(1.0 / 3.0);
  float alpha = 0.4f + 1.0f;       // boost: alpha < 1 -> alpha + 1
  float d = alpha - third;
  float c = third / sqrtf(d);

  u32 key0, key1, sk0, sk1;
  tf2x32(k0, k1, 0u, 0u, key0, key1);
  tf2x32(k0, k1, 0u, 1u, sk0, sk1);
  float u_boost = u01f(bits32(sk0, sk1, 0u));
  float boost = log1pf(-u_boost) * 2.5f;

  float X, V, U;
  do {
    u32 a0, a1, b0, b1, c0, c1;
    tf2x32(key0, key1, 0u, 0u, a0, a1);
    tf2x32(key0, key1, 0u, 1u, b0, b1);
    tf2x32(key0, key1, 0u, 2u, c0, c1);
    key0 = a0; key1 = a1;
    u32 xk0 = b0, xk1 = b1;
    float x, v;
    do {
      u32 n0, n1, s0, s1;
      tf2x32(xk0, xk1, 0u, 0u, n0, n1);
      tf2x32(xk0, xk1, 0u, 1u, s0, s1);
      x = normal_from_bits(bits32(s0, s1, 0u));
      v = 1.0f + x * c;
      xk0 = n0; xk1 = n1;
    } while (v <= 0.0f);
    X = x * x;
    V = (v * v) * v;
    U = u01f(bits32(c0, c1, 0u));
  } while ((U >= 1.0f - (0.0331f * X) * X) &&
           (logf(U) >= X * 0.5f + d * ((1.0f - V) + logf(V))));

  float lg = logf(d) + logf(V);
  return lg + boost;
}

__device__ float beta_04(u32 la0, u32 la1, u32 lb0, u32 lb1, u32 i) {
  u32 ka0, ka1, kb0, kb1;
  tf2x32(la0, la1, 0u, i, ka0, ka1);
  tf2x32(lb0, lb1, 0u, i, kb0, kb1);
  float lga = loggamma_alpha04(ka0, ka1);
  float lgb = loggamma_alpha04(kb0, kb1);
  float m = fmaxf(lga, lgb);
  float ga = expf(lga - m);
  float gb = expf(lgb - m);
  return ga / (ga + gb);
}

struct RK {
  u32 sel0, sel1, pick0, pick1, la0, la1, lb0, lb1, coin0, coin1;
  u32 drop0, drop1, scl0, scl1, gm0, gm1, gs0, gs1, noi0, noi1;
};
struct AK { RK r[3]; };

// ---------------- K1: merged small kernel -----------------------------------
// blocks [0, mb): one WAVE per (round,sample), ballot-parallel B-scan (meta)
// blocks [mb, mb+gb): per-(round,gene) scale (gene)
__global__ __launch_bounds__(256) void k_small(
    const int* __restrict__ ctx, const int* __restrict__ y,
    const float* __restrict__ cont, const int* __restrict__ cat,
    AK keys, int B, int D, int ncont, int ncat, int mb,
    float* __restrict__ lam_ws, int* __restrict__ jsel_ws,
    int* __restrict__ domix_ws, float* __restrict__ scale_ws,
    float* __restrict__ gscale_ws, float* __restrict__ out,
    unsigned long long o_ctx, unsigned long long o_y,
    unsigned long long o_cont, unsigned long long o_cat) {
  if ((int)blockIdx.x >= mb) {
    // ---- gene branch ----
    int t = ((int)blockIdx.x - mb) * 256 + threadIdx.x;
    if (t >= 3 * D) return;
    int a = t / D, d = t - a * D;
    RK rk = keys.r[a];
    float ug = u01f(bits32(rk.gm0, rk.gm1, (u32)d));
    float us = u01f(bits32(rk.gs0, rk.gs1, (u32)d));
    float gs = us * 0.4f + 0.8f;
    gscale_ws[t] = (ug < 0.2f) ? gs : 1.0f;         // GENE_P
    return;
  }
  // ---- meta branch ----
  int wv = threadIdx.x >> 6;
  int lane = threadIdx.x & 63;
  int t = blockIdx.x * 4 + wv;
  if (t >= 3 * B) return;
  int a = t / B, i = t - a * B;
  RK rk = keys.r[a];
  int yi = y[i], ci = ctx[i];

  int nch = (B + 63) >> 6;
  // pass 1: candidate count (same label, different ctx)
  int cnt = 0;
  for (int c = 0; c < nch; ++c) {
    int j = (c << 6) + lane;
    bool pred = false;
    if (j < B) pred = (y[j] == yi) && (ctx[j] != ci);
    u64 m = __ballot(pred);
    cnt += __popcll(m);
  }

  float usel = u01f(bits32(rk.sel0, rk.sel1, (u32)i));
  bool mixmask = usel < 0.3f;                       // MIXUP_P
  float upick = u01f(bits32(rk.pick0, rk.pick1, (u32)i));
  int kth = min((int)floorf(upick * (float)cnt), max(cnt - 1, 0));

  // pass 2: select the (kth+1)-th candidate in ascending j
  int jsel = 0, csum = 0;
  for (int c = 0; c < nch; ++c) {
    int j = (c << 6) + lane;
    bool pred = false;
    if (j < B) pred = (y[j] == yi) && (ctx[j] != ci);
    u64 m = __ballot(pred);
    int pc = __popcll(m);
    if (csum + pc > kth) {           // wave-uniform
      int r = kth - csum;
      for (int z = 0; z < r; ++z) m &= m - 1;   // drop r lowest set bits
      jsel = (c << 6) + __builtin_ctzll(m);
      break;
    }
    csum += pc;
  }

  float lam = beta_04(rk.la0, rk.la1, rk.lb0, rk.lb1, (u32)i);
  bool domix = mixmask && (cnt > 0);
  bool coin = u01f(bits32(rk.coin0, rk.coin1, (u32)i)) < 0.5f;
  int ctxnew = (domix && !coin) ? ctx[jsel] : ci;
  float uscale = u01f(bits32(rk.scl0, rk.scl1, (u32)i));
  float scale = uscale * 0.4f + 0.8f;               // [DS_MIN, DS_MAX]

  if (lane == 0) {
    lam_ws[t] = lam;
    jsel_ws[t] = jsel;
    domix_ws[t] = domix ? 1 : 0;
    scale_ws[t] = scale;
    out[o_ctx + (size_t)t] = (float)ctxnew;
    out[o_y + (size_t)t] = (float)yi;
    for (int c2 = 0; c2 < ncont; ++c2)
      out[o_cont + (size_t)t * ncont + c2] = cont[(size_t)i * ncont + c2];
    for (int c2 = 0; c2 < ncat; ++c2)
      out[o_cat + (size_t)t * ncat + c2] = (float)cat[(size_t)i * ncat + c2];
  }
}

// ---------------- K3: main (B,D) augmentation, 8 genes/thread ----------------
__global__ __launch_bounds__(256) void k_main(
    const float* __restrict__ x, AK keys, int B, int D,
    const float* __restrict__ lam_ws, const int* __restrict__ jsel_ws,
    const int* __restrict__ domix_ws, const float* __restrict__ scale_ws,
    const float* __restrict__ gscale_ws, float* __restrict__ out) {
  int q = blockIdx.x * blockDim.x + threadIdx.x;
  int d0 = q * 8;
  if (d0 >= D) return;
  int i = blockIdx.y;
  int a = blockIdx.z;
  int t = a * B + i;
  RK rk = keys.r[a];
  float lam = lam_ws[t];          // block-uniform -> scalar loads
  int jsel = jsel_ws[t];
  int domix = domix_ws[t];
  float scale = scale_ws[t];

  const float4* xip = (const float4*)(x + (size_t)i * D + d0);
  float4 xa = xip[0], xb = xip[1];
  float4 ja_ = xa, jb_ = xb;
  if (domix) {
    const float4* xjp = (const float4*)(x + (size_t)jsel * D + d0);
    ja_ = xjp[0]; jb_ = xjp[1];
  }
  const float4* gp = (const float4*)(gscale_ws + (size_t)a * D + d0);
  float4 ga = gp[0], gb = gp[1];

  float xiv[8] = {xa.x, xa.y, xa.z, xa.w, xb.x, xb.y, xb.z, xb.w};
  float xjv[8] = {ja_.x, ja_.y, ja_.z, ja_.w, jb_.x, jb_.y, jb_.z, jb_.w};
  float gv[8]  = {ga.x, ga.y, ga.z, ga.w, gb.x, gb.y, gb.z, gb.w};
  float oml = 1.0f - lam;
  u32 base = (u32)(i * D + d0);

  float r[8];
#pragma unroll
  for (int e = 0; e < 8; ++e) {
    u32 idx = base + (u32)e;
    u32 bd = bits32(rk.drop0, rk.drop1, idx);
    bool keep = bd >= 0x33333400u;       // == u01f(bd) > 0.2f, bit-exact
    u32 bn = bits32(rk.noi0, rk.noi1, idx);
    float u;
    float pc = noise_coef(bn, u);        // noise = fma(pc, u, v)
    float bse = domix ? __builtin_fmaf(lam, xiv[e], oml * xjv[e]) : xiv[e];
    float v = keep ? bse * (scale * gv[e]) : 0.0f;
    r[e] = fmaxf(__builtin_fmaf(pc, u, v), 0.0f);
  }
  float4 o0; o0.x = r[0]; o0.y = r[1]; o0.z = r[2]; o0.w = r[3];
  float4 o1; o1.x = r[4]; o1.y = r[5]; o1.z = r[6]; o1.w = r[7];
  float4* op = (float4*)(out + (size_t)a * B * D + (size_t)i * D + d0);
  op[0] = o0; op[1] = o1;
}

// ---------------- host ----------------
extern "C" void kernel_launch(void* const* d_in, const int* in_sizes, int n_in,
                              void* d_out, int out_size, void* d_ws, size_t ws_size,
                              hipStream_t stream) {
  const float* x = (const float*)d_in[0];
  const int* ctx = (const int*)d_in[1];
  const int* y = (const int*)d_in[2];
  const float* cont = (const float*)d_in[3];
  const int* cat = (const int*)d_in[4];
  int B = in_sizes[1];
  int D = in_sizes[0] / B;
  int ncont = in_sizes[3] / B;
  int ncat = in_sizes[4] / B;

  // Host-side threefry key schedule (pure integer math; no HIP calls).
  AK keys;
  u32 b0 = 0u, b1 = 42u;  // jax.random.key(42) -> [0, 42]
  for (int a = 0; a < 3; ++a) {
    u32 k0, k1;
    tf2x32(b0, b1, 0u, (u32)a, k0, k1);             // fold_in(base, a)
    u32 m0, m1;
    tf2x32(k0, k1, 0u, 0u, m0, m1);                 // k_mix
    tf2x32(k0, k1, 0u, 1u, keys.r[a].drop0, keys.r[a].drop1);   // k_drop
    tf2x32(k0, k1, 0u, 2u, keys.r[a].scl0, keys.r[a].scl1);     // k_scale
    tf2x32(k0, k1, 0u, 3u, keys.r[a].gm0, keys.r[a].gm1);       // k_gmask
    tf2x32(k0, k1, 0u, 4u, keys.r[a].gs0, keys.r[a].gs1);       // k_gscale
    tf2x32(k0, k1, 0u, 5u, keys.r[a].noi0, keys.r[a].noi1);     // k_noise
    tf2x32(m0, m1, 0u, 0u, keys.r[a].sel0, keys.r[a].sel1);     // k_sel
    tf2x32(m0, m1, 0u, 1u, keys.r[a].pick0, keys.r[a].pick1);   // k_pick
    u32 l0, l1;
    tf2x32(m0, m1, 0u, 2u, l0, l1);                             // k_lam
    tf2x32(m0, m1, 0u, 3u, keys.r[a].coin0, keys.r[a].coin1);   // k_coin
    tf2x32(l0, l1, 0u, 0u, keys.r[a].la0, keys.r[a].la1);       // beta key_a
    tf2x32(l0, l1, 0u, 1u, keys.r[a].lb0, keys.r[a].lb1);       // beta key_b
  }

  // workspace carve-up
  float* lam_ws = (float*)d_ws;
  int* jsel_ws = (int*)(lam_ws + (size_t)3 * B);
  int* domix_ws = jsel_ws + (size_t)3 * B;
  float* scale_ws = (float*)(domix_ws + (size_t)3 * B);
  float* gscale_ws = scale_ws + (size_t)3 * B;

  float* out = (float*)d_out;
  size_t BD = (size_t)B * D;
  unsigned long long o_ctx = 3ull * BD;
  unsigned long long o_y = o_ctx + 3ull * B;
  unsigned long long o_cont = o_y + 3ull * B;
  unsigned long long o_cat = o_cont + 3ull * (size_t)B * ncont;

  // K1: merged meta (one wave per (round,sample)) + gene
  int mb = (3 * B + 3) / 4;                 // meta blocks (4 waves/block)
  int gb = (3 * D + 255) / 256;             // gene blocks
  k_small<<<mb + gb, 256, 0, stream>>>(
      ctx, y, cont, cat, keys, B, D, ncont, ncat, mb,
      lam_ws, jsel_ws, domix_ws, scale_ws, gscale_ws, out,
      o_ctx, o_y, o_cont, o_cat);

  // K3: 8 genes/thread
  int nq = (D + 7) / 8;
  dim3 grid((nq + 255) / 256, B, 3);
  k_main<<<grid, 256, 0, stream>>>(x, keys, B, D, lam_ws, jsel_ws, domix_ws,
                                   scale_ws, gscale_ws, out);
}